// Round 12
// baseline (662.450 us; speedup 1.0000x reference)
//
#include <hip/hip_runtime.h>
#include <hip/hip_bf16.h>
#include <cstdint>

// Problem constants
#define BB 2
#define SS 2048
#define HID 2048
#define NH 16
#define NKV 4
#define HD 128
#define SCALE_ 0.08838834764831845f   // 128^-0.5
#define EPS_ 1e-6f

typedef __bf16 bf16;
typedef __attribute__((ext_vector_type(8))) __bf16 bf16x8;
typedef __attribute__((ext_vector_type(4))) __bf16 bf16x4;
typedef __attribute__((ext_vector_type(4))) float f32x4;

__device__ __forceinline__ void g2l16(const bf16* src, void* dst) {
  __builtin_amdgcn_global_load_lds(
      (const __attribute__((address_space(1))) void*)src,
      (__attribute__((address_space(3))) void*)dst, 16, 0, 0);
}

// ---------------- rope tables: cos/sin [S][32] ----------------
__global__ __launch_bounds__(256) void rope_tables_k(float* __restrict__ C, float* __restrict__ Sn) {
  int idx = blockIdx.x * 256 + threadIdx.x;   // S*32 = 65536
  int s = idx >> 5, j = idx & 31;
  float inv = powf(10000.f, -(float)j / 32.f);
  float f = (float)s * inv;
  C[idx] = cosf(f);
  Sn[idx] = sinf(f);
}

// ---------------- f32 -> bf16 convert ----------------
__global__ __launch_bounds__(256) void cvt_k(const float* __restrict__ src, bf16* __restrict__ dst, int n) {
  int i = (blockIdx.x * 256 + threadIdx.x) * 4;
  if (i >= n) return;
  f32x4 v = *(const f32x4*)(src + i);
  bf16x4 o;
  o[0] = (bf16)v[0]; o[1] = (bf16)v[1]; o[2] = (bf16)v[2]; o[3] = (bf16)v[3];
  *(bf16x4*)(dst + i) = o;
}

// ---------------- f32 -> bf16 convert with row interleave (rows 2j+off) ----------------
// src [8192][2048] f32 -> dst rows (2j+off) of [16384][2048] bf16
__global__ __launch_bounds__(256) void cvt2_k(const float* __restrict__ src, bf16* __restrict__ dst, int off) {
  int i = (blockIdx.x * 256 + threadIdx.x) * 4;      // 16777216 elems
  f32x4 v = *(const f32x4*)(src + i);
  size_t d = ((size_t)(i >> 11) * 2 + off) * 2048 + (i & 2047);
  bf16x4 o;
  o[0] = (bf16)v[0]; o[1] = (bf16)v[1]; o[2] = (bf16)v[2]; o[3] = (bf16)v[3];
  *(bf16x4*)(dst + d) = o;
}

// ---------------- RMSNorm: f32 row[2048] -> bf16 ----------------
__global__ __launch_bounds__(256) void rmsnorm_k(const float* __restrict__ X, const float* __restrict__ W,
                                                 bf16* __restrict__ Out) {
  const int row = blockIdx.x;
  const float* xr = X + (size_t)row * 2048;
  const int t = threadIdx.x;
  f32x4 a = *(const f32x4*)(xr + t * 8);
  f32x4 b = *(const f32x4*)(xr + t * 8 + 4);
  float ss = a[0]*a[0] + a[1]*a[1] + a[2]*a[2] + a[3]*a[3]
           + b[0]*b[0] + b[1]*b[1] + b[2]*b[2] + b[3]*b[3];
  #pragma unroll
  for (int m = 1; m <= 32; m <<= 1) ss += __shfl_xor(ss, m);
  __shared__ float red[4];
  if ((t & 63) == 0) red[t >> 6] = ss;
  __syncthreads();
  ss = red[0] + red[1] + red[2] + red[3];
  float sc = rsqrtf(ss * (1.f / 2048.f) + EPS_);
  const float* wp = W + t * 8;
  float v[8] = {a[0], a[1], a[2], a[3], b[0], b[1], b[2], b[3]};
  bf16x8 o;
  #pragma unroll
  for (int j = 0; j < 8; j++) o[j] = (bf16)(v[j] * sc * wp[j]);
  *(bf16x8*)(Out + (size_t)row * 2048 + t * 8) = o;
}

// ---------------- QK-RMSNorm + RoPE ----------------
__global__ __launch_bounds__(256) void qknorm_rope_k(const bf16* __restrict__ QKV,
                                                     const float* __restrict__ QW, const float* __restrict__ KW,
                                                     const float* __restrict__ C, const float* __restrict__ Sn,
                                                     bf16* __restrict__ Qo, bf16* __restrict__ Ko) {
  const int row = blockIdx.x;          // b*S+s
  const int s = row & (SS - 1);
  const bf16* qr = QKV + (size_t)row * 3072;
  const int t = threadIdx.x;

  bf16x8 qv = *(const bf16x8*)(qr + t * 8);
  float qvf[8];
  float ssq = 0.f, ssk = 0.f;
  #pragma unroll
  for (int j = 0; j < 8; j++) { qvf[j] = (float)qv[j]; ssq += qvf[j] * qvf[j]; }
  float kvf[8];
  if (t < 64) {
    bf16x8 kv = *(const bf16x8*)(qr + 2048 + t * 8);
    #pragma unroll
    for (int j = 0; j < 8; j++) { kvf[j] = (float)kv[j]; ssk += kvf[j] * kvf[j]; }
  }
  #pragma unroll
  for (int m = 1; m <= 32; m <<= 1) { ssq += __shfl_xor(ssq, m); ssk += __shfl_xor(ssk, m); }
  __shared__ float redq[4], redk[4];
  if ((t & 63) == 0) { redq[t >> 6] = ssq; redk[t >> 6] = ssk; }
  __syncthreads();
  ssq = redq[0] + redq[1] + redq[2] + redq[3];
  ssk = redk[0] + redk[1] + redk[2] + redk[3];
  const float scq = rsqrtf(ssq * (1.f / 2048.f) + EPS_);
  const float sck = rsqrtf(ssk * (1.f / 512.f) + EPS_);

  const float* cb = C + s * 32;
  const float* sb = Sn + s * 32;

  {
    int e = t * 8, dh = e & 127;
    float nv[8];
    #pragma unroll
    for (int j = 0; j < 8; j++) nv[j] = qvf[j] * scq * QW[e + j];
    if (dh < 64) {
      int pe = (dh < 32) ? e + 32 : e - 32;
      bf16x8 pv = *(const bf16x8*)(qr + pe);
      #pragma unroll
      for (int j = 0; j < 8; j++) {
        float pf = (float)pv[j] * scq * QW[pe + j];
        float c = cb[(dh + j) & 31], sn = sb[(dh + j) & 31];
        nv[j] = (dh < 32) ? (nv[j] * c - pf * sn) : (nv[j] * c + pf * sn);
      }
    }
    bf16x8 o;
    #pragma unroll
    for (int j = 0; j < 8; j++) o[j] = (bf16)nv[j];
    *(bf16x8*)(Qo + (size_t)row * 2048 + e) = o;
  }
  if (t < 64) {
    int e = t * 8, dh = e & 127;
    float nv[8];
    #pragma unroll
    for (int j = 0; j < 8; j++) nv[j] = kvf[j] * sck * KW[e + j];
    if (dh < 64) {
      int pe = (dh < 32) ? e + 32 : e - 32;
      bf16x8 pv = *(const bf16x8*)(qr + 2048 + pe);
      #pragma unroll
      for (int j = 0; j < 8; j++) {
        float pf = (float)pv[j] * sck * KW[pe + j];
        float c = cb[(dh + j) & 31], sn = sb[(dh + j) & 31];
        nv[j] = (dh < 32) ? (nv[j] * c - pf * sn) : (nv[j] * c + pf * sn);
      }
    }
    bf16x8 o;
    #pragma unroll
    for (int j = 0; j < 8; j++) o[j] = (bf16)nv[j];
    *(bf16x8*)(Ko + (size_t)row * 512 + e) = o;
  }
}

// ---------------- V transpose: qkv v-part -> Vt[B,HK,D,S] ----------------
__global__ __launch_bounds__(256) void vtrans_k(const bf16* __restrict__ QKV, bf16* __restrict__ Vt) {
  const int blk = blockIdx.x;              // B*HK*(S/64) = 256
  const int st = blk & 31, kh = (blk >> 5) & 3, b = blk >> 7;
  const int s0 = st << 6;
  __shared__ __align__(16) bf16 tile[64][136];
  const int t = threadIdx.x;
  {
    const int s = t >> 2, c = (t & 3) * 32;
    const bf16* src = QKV + (size_t)(b * SS + s0 + s) * 3072 + 2560 + kh * 128 + c;
    #pragma unroll
    for (int j = 0; j < 4; j++)
      *(bf16x8*)(&tile[s][c + j * 8]) = *(const bf16x8*)(src + j * 8);
  }
  __syncthreads();
  {
    const int d = t >> 1, sh = (t & 1) * 32;
    bf16* dst = Vt + ((size_t)(b * NKV + kh) * HD + d) * SS + s0 + sh;
    #pragma unroll
    for (int j4 = 0; j4 < 4; j4++) {
      bf16x8 o;
      #pragma unroll
      for (int jj = 0; jj < 8; jj++) o[jj] = tile[sh + j4 * 8 + jj][d];
      *(bf16x8*)(dst + j4 * 8) = o;
    }
  }
}

// ---------------- GEMM: C[M,N] = A[M,K] @ W[N,K]^T (128x128, BK=64) ----------------
// Supertile column-groups-of-8 + XCD swizzle; non-dual: dbuf issue-early/wait-late (R10 win);
// dual path retained but unused this round.
template <int EPI>
__global__ __launch_bounds__(256, 2) void gemm_bt(const bf16* __restrict__ A, const bf16* __restrict__ W0,
                                                  const bf16* __restrict__ W1, bf16* __restrict__ Cb,
                                                  float* __restrict__ Cf, const float* __restrict__ resid,
                                                  int M, int N, int K) {
  constexpr bool DUAL = (EPI == 2);
  constexpr bool DBUF = !DUAL;
  constexpr int TB = DUAL ? 49152 : 32768;
  __shared__ __align__(16) char smem[DBUF ? 2 * TB : TB];

  const int nbn = N >> 7;
  const int nbm = M >> 7;
  const int nwg = gridDim.x;
  const int per = nwg >> 3;
  const int bid = blockIdx.x;
  const int swz = (bid & 7) * per + (bid >> 3);
  const int gsz = nbm << 3;
  const int g = swz / gsz;
  const int rr = swz - g * gsz;
  const int by = rr >> 3;
  const int bx = (g << 3) + (rr & 7);
  const int m0 = by << 7, n0 = bx << 7;
  (void)nbn;

  const int t = threadIdx.x;
  const int lane = t & 63, wid = t >> 6;
  const int wr = (wid >> 1) * 64, wc = (wid & 1) * 64;
  const int lr = lane & 15, lg = lane >> 4;

  f32x4 acc[4][4], acc3[4][4];
  #pragma unroll
  for (int i = 0; i < 4; i++)
    #pragma unroll
    for (int j = 0; j < 4; j++) {
      acc[i][j] = (f32x4)0.f;
      if constexpr (DUAL) acc3[i][j] = (f32x4)0.f;
    }

  const int srow = t >> 3;
  const int sc8 = t & 7;

  auto stage = [&](int k0, char* base) {
    #pragma unroll
    for (int i = 0; i < 4; i++) {
      int row = i * 32 + srow;
      int csw = sc8 ^ (row & 7);
      g2l16(A + (size_t)(m0 + row) * K + k0 + csw * 8, base + i * 4096 + t * 16);
    }
    #pragma unroll
    for (int i = 0; i < 4; i++) {
      int row = i * 32 + srow;
      int csw = sc8 ^ (row & 7);
      g2l16(W0 + (size_t)(n0 + row) * K + k0 + csw * 8, base + 16384 + i * 4096 + t * 16);
    }
    if constexpr (DUAL) {
      #pragma unroll
      for (int i = 0; i < 4; i++) {
        int row = i * 32 + srow;
        int csw = sc8 ^ (row & 7);
        g2l16(W1 + (size_t)(n0 + row) * K + k0 + csw * 8, base + 32768 + i * 4096 + t * 16);
      }
    }
  };

  auto compute = [&](const char* cur) {
    #pragma unroll
    for (int kk = 0; kk < 2; kk++) {
      bf16x8 af[4];
      #pragma unroll
      for (int mi = 0; mi < 4; mi++) {
        int row = wr + mi * 16 + lr;
        int ch = (kk * 4 + lg) ^ (row & 7);
        af[mi] = *(const bf16x8*)(cur + row * 128 + ch * 16);
      }
      #pragma unroll
      for (int ni = 0; ni < 4; ni++) {
        int rowb = wc + ni * 16 + lr;
        int chb = (kk * 4 + lg) ^ (rowb & 7);
        bf16x8 bb = *(const bf16x8*)(cur + 16384 + rowb * 128 + chb * 16);
        #pragma unroll
        for (int mi = 0; mi < 4; mi++)
          acc[mi][ni] = __builtin_amdgcn_mfma_f32_16x16x32_bf16(af[mi], bb, acc[mi][ni], 0, 0, 0);
        if constexpr (DUAL) {
          bf16x8 b3 = *(const bf16x8*)(cur + 32768 + rowb * 128 + chb * 16);
          #pragma unroll
          for (int mi = 0; mi < 4; mi++)
            acc3[mi][ni] = __builtin_amdgcn_mfma_f32_16x16x32_bf16(af[mi], b3, acc3[mi][ni], 0, 0, 0);
        }
      }
    }
  };

  if constexpr (DBUF) {
    stage(0, smem);
    asm volatile("s_waitcnt vmcnt(0)" ::: "memory");
    __builtin_amdgcn_s_barrier();
    for (int k0 = 0; k0 < K; k0 += 64) {
      char* cur = smem + (((k0 >> 6) & 1) ? TB : 0);
      char* nxt = smem + (((k0 >> 6) & 1) ? 0 : TB);
      if (k0 + 64 < K) stage(k0 + 64, nxt);
      compute(cur);
      asm volatile("s_waitcnt vmcnt(0)" ::: "memory");
      __builtin_amdgcn_s_barrier();
    }
  } else {
    for (int k0 = 0; k0 < K; k0 += 64) {
      __syncthreads();
      stage(k0, smem);
      __syncthreads();
      compute(smem);
    }
  }

  #pragma unroll
  for (int mi = 0; mi < 4; mi++)
    #pragma unroll
    for (int ni = 0; ni < 4; ni++)
      #pragma unroll
      for (int r = 0; r < 4; r++) {
        int m = m0 + wr + mi * 16 + lg * 4 + r;
        int n = n0 + wc + ni * 16 + lr;
        size_t idx = (size_t)m * N + n;
        if constexpr (EPI == 0) {
          Cb[idx] = (bf16)acc[mi][ni][r];
        } else if constexpr (EPI == 1) {
          Cf[idx] = resid[idx] + acc[mi][ni][r];
        } else {
          float g_ = acc[mi][ni][r], u = acc3[mi][ni][r];
          Cb[idx] = (bf16)(g_ * u / (1.f + __expf(-g_)));
        }
      }
}

// ---------------- SwiGLU 8-phase 256x256 GEMM (interleaved W13) ----------------
// C[m][n] = h @ W13I^T with W13I rows interleaved (2j = w1_j, 2j+1 = w3_j); epilogue pairs
// (g,u) via shfl_xor(1) and writes silu(g)*u to Out[4096][8192].
// m201-class schedule, derived + hazard-checked: 8 waves 2Mx4N (wave 128x64, acc 128 VGPR),
// A/B each 2x32KB slots (tile parity), 128KB LDS. Per (T,T+1) 8 phases; stages:
// ph2:B(T+2)h0  ph3:B(T+2)h1+A(T+2)h0  ph4:A(T+2)h1  ph6:B(T+3)h0,h1  ph7:A(T+3)h0,h1
// (every stage >=1 barrier after its slot's last reader). Counted waits: vmcnt(6)@ph3-end
// (prev ph6/ph7 = tile T+1 landed), vmcnt(8)@ph7-end (tile T+2 landed) -- never 0 in loop.
// Guarded main loop (T <= NT-4) + vmcnt(0)-drained straight-line tail for last 2 tiles.
__global__ __launch_bounds__(512, 2) void gemm_sw(const bf16* __restrict__ A, const bf16* __restrict__ W,
                                                  bf16* __restrict__ Out) {
  constexpr int Kc = 2048;
  constexpr int NT = Kc >> 6;                 // 32
  __shared__ __align__(16) char smem[131072]; // A slots [0,64K), B slots [64K,128K)

  const int nbm = 16;
  const int per = gridDim.x >> 3;             // 128
  const int bid = blockIdx.x;
  const int swz = (bid & 7) * per + (bid >> 3);
  const int gsz = nbm << 3;                   // 128
  const int g = swz / gsz, rr = swz - g * gsz;
  const int by = rr >> 3, bx = (g << 3) + (rr & 7);
  const int m0 = by << 8, n0 = bx << 8;

  const int t = threadIdx.x;
  const int lane = t & 63;
  const int wid = t >> 6;
  const int lr = lane & 15, lg = lane >> 4;
  const int wm = wid >> 2, wn = wid & 3;

  const int srow = t >> 3;                    // 0..63
  const int gko = ((t & 7) ^ (srow & 7)) * 8; // pre-swizzled k offset (elements)

  auto stA = [&](int tile, int half) {        // 2 loads (rows half*128 + srow, +64)
    const bf16* s = A + (size_t)(m0 + half * 128 + srow) * Kc + (tile << 6) + gko;
    char* d = smem + (tile & 1) * 32768 + half * 16384 + t * 16;
    g2l16(s, d);
    g2l16(s + (size_t)64 * Kc, d + 8192);
  };
  auto stB = [&](int tile, int half) {
    const bf16* s = W + (size_t)(n0 + half * 128 + srow) * Kc + (tile << 6) + gko;
    char* d = smem + 65536 + (tile & 1) * 32768 + half * 16384 + t * 16;
    g2l16(s, d);
    g2l16(s + (size_t)64 * Kc, d + 8192);
  };

  f32x4 acc[8][4];
  #pragma unroll
  for (int i = 0; i < 8; i++)
    #pragma unroll
    for (int j = 0; j < 4; j++) acc[i][j] = (f32x4)0.f;

  bf16x8 af[4][2], bL[2][2], bH[2][2];
  const int fsw = lr & 7;

  auto rdA = [&](const char* base, int mi0) {
    #pragma unroll
    for (int mi = 0; mi < 4; mi++)
      #pragma unroll
      for (int kk = 0; kk < 2; kk++) {
        int row = wm * 128 + (mi0 + mi) * 16 + lr;
        af[mi][kk] = *(const bf16x8*)(base + row * 128 + (((kk * 4 + lg) ^ fsw) << 4));
      }
  };
  auto rdB = [&](const char* base, bf16x8 (*dst)[2], int ni0) {
    #pragma unroll
    for (int ni = 0; ni < 2; ni++)
      #pragma unroll
      for (int kk = 0; kk < 2; kk++) {
        int row = wn * 64 + (ni0 + ni) * 16 + lr;
        dst[ni][kk] = *(const bf16x8*)(base + row * 128 + (((kk * 4 + lg) ^ fsw) << 4));
      }
  };
  auto mma = [&](int mO, bf16x8 (*B)[2], int nO) {
    #pragma unroll
    for (int ni = 0; ni < 2; ni++)
      #pragma unroll
      for (int mi = 0; mi < 4; mi++)
        #pragma unroll
        for (int kk = 0; kk < 2; kk++)
          acc[mO + mi][nO + ni] =
              __builtin_amdgcn_mfma_f32_16x16x32_bf16(af[mi][kk], B[ni][kk], acc[mO + mi][nO + ni], 0, 0, 0);
  };

#define BARR() asm volatile("s_barrier" ::: "memory")
#define PH_SYNC() BARR(); asm volatile("s_waitcnt lgkmcnt(0)" ::: "memory"); __builtin_amdgcn_sched_barrier(0)
#define P1() __builtin_amdgcn_s_setprio(1)
#define P0() __builtin_amdgcn_s_setprio(0)

  // prologue: stage tiles 0,1 fully (16 loads; first 8 = tile 0)
  stA(0, 0); stA(0, 1); stB(0, 0); stB(0, 1);
  stA(1, 0); stA(1, 1); stB(1, 0); stB(1, 1);
  asm volatile("s_waitcnt vmcnt(8)" ::: "memory");
  BARR();

  for (int T = 0; T <= NT - 4; T += 2) {
    const char* A0 = smem + (T & 1) * 32768;
    const char* B0 = smem + 65536 + (T & 1) * 32768;
    const char* A1 = smem + ((T + 1) & 1) * 32768;
    const char* B1 = smem + 65536 + ((T + 1) & 1) * 32768;
    // ---- tile T ----
    // ph0: (miL, niL)
    rdA(A0, 0); rdB(B0, bL, 0);
    PH_SYNC(); P1(); mma(0, bL, 0); P0(); BARR();
    // ph1: (miL, niH)
    rdB(B0, bH, 2);
    PH_SYNC(); P1(); mma(0, bH, 2); P0(); BARR();
    // ph2: (miH, niL)  [stage B(T+2).h0 -- B(T) fully read after ph1]
    rdA(A0, 4);
    stB(T + 2, 0);
    PH_SYNC(); P1(); mma(4, bL, 0); P0(); BARR();
    // ph3: (miH, niH)  [stage B(T+2).h1, A(T+2).h0 -- A(T) fully read after ph2]
    stB(T + 2, 1); stA(T + 2, 0);
    P1(); mma(4, bH, 2); P0();
    asm volatile("s_waitcnt vmcnt(6)" ::: "memory");   // prev ph6/ph7 (= tile T+1) landed
    BARR();
    // ---- tile T+1 ----
    // ph4
    rdA(A1, 0); rdB(B1, bL, 0);
    stA(T + 2, 1);
    PH_SYNC(); P1(); mma(0, bL, 0); P0(); BARR();
    // ph5
    rdB(B1, bH, 2);
    PH_SYNC(); P1(); mma(0, bH, 2); P0(); BARR();
    // ph6  [stage B(T+3) both halves -- B(T+1) fully read after ph5]
    rdA(A1, 4);
    stB(T + 3, 0); stB(T + 3, 1);
    PH_SYNC(); P1(); mma(4, bL, 0); P0(); BARR();
    // ph7  [stage A(T+3) both halves -- A(T+1) fully read after ph6]
    stA(T + 3, 0); stA(T + 3, 1);
    P1(); mma(4, bH, 2); P0();
    asm volatile("s_waitcnt vmcnt(8)" ::: "memory");   // tile T+2 fully landed
    BARR();
  }

  // tail: tiles NT-2, NT-1 (staged by last main iter); drain, then straight-line compute
  asm volatile("s_waitcnt vmcnt(0)" ::: "memory");
  BARR();
  {
    const int T = NT - 2;
    const char* A0 = smem + (T & 1) * 32768;
    const char* B0 = smem + 65536 + (T & 1) * 32768;
    const char* A1 = smem + ((T + 1) & 1) * 32768;
    const char* B1 = smem + 65536 + ((T + 1) & 1) * 32768;
    rdA(A0, 0); rdB(B0, bL, 0); mma(0, bL, 0);
    rdB(B0, bH, 2); mma(0, bH, 2);
    rdA(A0, 4); mma(4, bL, 0); mma(4, bH, 2);
    rdA(A1, 0); rdB(B1, bL, 0); mma(0, bL, 0);
    rdB(B1, bH, 2); mma(0, bH, 2);
    rdA(A1, 4); mma(4, bL, 0); mma(4, bH, 2);
  }
#undef BARR
#undef PH_SYNC
#undef P1
#undef P0

  // epilogue: n = n0 + wn*64 + ni*16 + lr (parity: even=g, odd=u); pair via shfl_xor(1);
  // even lanes write silu(g)*u to Out[m][n>>1].
  #pragma unroll
  for (int mi = 0; mi < 8; mi++)
    #pragma unroll
    for (int ni = 0; ni < 4; ni++)
      #pragma unroll
      for (int r = 0; r < 4; r++) {
        float v = acc[mi][ni][r];
        float p = __shfl_xor(v, 1);
        float gg = (lane & 1) ? p : v;
        float uu = (lane & 1) ? v : p;
        float res = gg * uu / (1.f + __expf(-gg));
        if (!(lane & 1)) {
          int m = m0 + wm * 128 + mi * 16 + lg * 4 + r;
          int oc = (n0 >> 1) + wn * 32 + ni * 8 + (lr >> 1);
          Out[(size_t)m * 8192 + oc] = (bf16)res;
        }
      }
}

// ---------------- Sliding-window GQA flash attention ----------------
__global__ __launch_bounds__(256, 2) void attn_kernel(const bf16* __restrict__ Q, const bf16* __restrict__ Kr,
                                                      const bf16* __restrict__ Vt, bf16* __restrict__ O) {
  __shared__ __align__(16) char smem[41984];
  const int qt = blockIdx.x, h = blockIdx.y, b = blockIdx.z;
  const int kh = h >> 2;
  const int q0 = qt << 6;
  const int t = threadIdx.x, lane = t & 63, wid = t >> 6;
  const int lr = lane & 15, lg = lane >> 4;

  bf16x8 qf[4];
  {
    const bf16* qb = Q + (((size_t)b * SS + q0 + wid * 16 + lr) * NH + h) * HD;
    #pragma unroll
    for (int c = 0; c < 4; c++) qf[c] = *(const bf16x8*)(qb + c * 32 + lg * 8);
  }
  f32x4 of[8];
  #pragma unroll
  for (int i = 0; i < 8; i++) of[i] = (f32x4)0.f;
  float m_[4] = {-1e30f, -1e30f, -1e30f, -1e30f};
  float l_[4] = {0.f, 0.f, 0.f, 0.f};

  const int kt_lo = qt >= 8 ? qt - 8 : 0;
  for (int kt = kt_lo; kt <= qt; kt++) {
    const int k0 = kt << 6;
    __syncthreads();
    {
      int rb = t >> 4, c = t & 15;
      #pragma unroll
      for (int i = 0; i < 4; i++) {
        int r = i * 16 + rb;
        int csw = c ^ (r & 7);
        g2l16(Kr + (((size_t)b * SS + k0 + r) * NKV + kh) * HD + csw * 8, smem + i * 4096 + t * 16);
      }
    }
    {
      int rb = t >> 3, c = t & 7;
      #pragma unroll
      for (int i = 0; i < 4; i++) {
        int r = i * 32 + rb;
        int csw = c ^ (r & 7);
        g2l16(Vt + ((size_t)(b * NKV + kh) * HD + r) * SS + k0 + csw * 8, smem + 16384 + i * 4096 + t * 16);
      }
    }
    __syncthreads();

    f32x4 sf[4];
    #pragma unroll
    for (int nt = 0; nt < 4; nt++) {
      sf[nt] = (f32x4)0.f;
      #pragma unroll
      for (int c = 0; c < 4; c++) {
        int row = nt * 16 + lr;
        int ch = (c * 4 + lg) ^ (row & 7);
        bf16x8 kf = *(const bf16x8*)(smem + row * 256 + ch * 16);
        sf[nt] = __builtin_amdgcn_mfma_f32_16x16x32_bf16(qf[c], kf, sf[nt], 0, 0, 0);
      }
    }
    #pragma unroll
    for (int r = 0; r < 4; r++) {
      int q = q0 + wid * 16 + lg * 4 + r;
      float mx = -1e30f;
      #pragma unroll
      for (int nt = 0; nt < 4; nt++) {
        int k = k0 + nt * 16 + lr;
        float s = sf[nt][r] * SCALE_;
        s = (k <= q && k + 512 >= q) ? s : -1e30f;
        sf[nt][r] = s;
        mx = fmaxf(mx, s);
      }
      mx = fmaxf(mx, __shfl_xor(mx, 1));
      mx = fmaxf(mx, __shfl_xor(mx, 2));
      mx = fmaxf(mx, __shfl_xor(mx, 4));
      mx = fmaxf(mx, __shfl_xor(mx, 8));
      float mnew = fmaxf(m_[r], mx);
      float corr = __expf(m_[r] - mnew);
      float rs = 0.f;
      #pragma unroll
      for (int nt = 0; nt < 4; nt++) {
        float p = __expf(sf[nt][r] - mnew);
        sf[nt][r] = p;
        rs += p;
      }
      rs += __shfl_xor(rs, 1); rs += __shfl_xor(rs, 2);
      rs += __shfl_xor(rs, 4); rs += __shfl_xor(rs, 8);
      l_[r] = l_[r] * corr + rs;
      m_[r] = mnew;
      #pragma unroll
      for (int dt = 0; dt < 8; dt++) of[dt][r] *= corr;
    }
    bf16* Pl = (bf16*)(smem + 32768 + wid * 2304);
    #pragma unroll
    for (int nt = 0; nt < 4; nt++)
      #pragma unroll
      for (int r = 0; r < 4; r++)
        Pl[(lg * 4 + r) * 72 + nt * 16 + lr] = (bf16)sf[nt][r];
    bf16x8 pf[2];
    #pragma unroll
    for (int c = 0; c < 2; c++) pf[c] = *(const bf16x8*)(Pl + lr * 72 + c * 32 + lg * 8);
    #pragma unroll
    for (int dt = 0; dt < 8; dt++) {
      #pragma unroll
      for (int c = 0; c < 2; c++) {
        int row = dt * 16 + lr;
        int ch = (c * 4 + lg) ^ (row & 7);
        bf16x8 vf = *(const bf16x8*)(smem + 16384 + row * 128 + ch * 16);
        of[dt] = __builtin_amdgcn_mfma_f32_16x16x32_bf16(pf[c], vf, of[dt], 0, 0, 0);
      }
    }
  }
  #pragma unroll
  for (int dt = 0; dt < 8; dt++)
    #pragma unroll
    for (int r = 0; r < 4; r++) {
      int q = q0 + wid * 16 + lg * 4 + r;
      O[(((size_t)b * SS + q) * NH + h) * HD + dt * 16 + lr] = (bf16)(of[dt][r] / l_[r]);
    }
}

// ---------------- launch ----------------
extern "C" void kernel_launch(void* const* d_in, const int* in_sizes, int n_in,
                              void* d_out, int out_size, void* d_ws, size_t ws_size,
                              hipStream_t stream) {
  (void)in_sizes; (void)n_in; (void)out_size; (void)ws_size;
  const float* x   = (const float*)d_in[0];
  const float* wq  = (const float*)d_in[1];
  const float* wk  = (const float*)d_in[2];
  const float* wv  = (const float*)d_in[3];
  const float* wo  = (const float*)d_in[4];
  const float* qnw = (const float*)d_in[5];
  const float* knw = (const float*)d_in[6];
  const float* ln1 = (const float*)d_in[7];
  const float* ln2 = (const float*)d_in[8];
  const float* w1  = (const float*)d_in[9];
  const float* w2  = (const float*)d_in[10];
  const float* w3  = (const float*)d_in[11];
  float* out = (float*)d_out;
  char* ws = (char*)d_ws;

  bf16* W0  = (bf16*)(ws + 0);            // wqkv -> wo -> W13I -> w2 (region reused)
  bf16* QKV = (bf16*)(ws + 12582912);     // [4096,3072] bf16
  bf16* QRO = (bf16*)(ws + 37748736);     // [4096,2048] bf16
  bf16* KRO = (bf16*)(ws + 54525952);     // [4096,512] bf16
  bf16* ATT = (bf16*)(ws + 58720256);     // [4096,2048] bf16
  bf16* VT  = (bf16*)(ws + 75497472);     // [B,HK,D,S] bf16
  bf16* HBF = (bf16*)(ws + 79691776);     // [4096,2048] bf16 (ln1 out, later ln2 out)
  bf16* ACT = (bf16*)(ws + 96468992);     // [4096,8192] bf16
  float* COS = (float*)(ws + 163577856);
  float* SIN = (float*)(ws + 163577856 + 262144);
  bf16* W13I = (bf16*)ws;                 // interleaved w1/w3 [16384,2048], after region A dead
  bf16* W2B = (bf16*)ws;                  // w2, after SwiGLU gemm

  rope_tables_k<<<256, 256, 0, stream>>>(COS, SIN);
  cvt_k<<<4096, 256, 0, stream>>>(wq, W0, 4194304);
  cvt_k<<<1024, 256, 0, stream>>>(wk, W0 + 4194304, 1048576);
  cvt_k<<<1024, 256, 0, stream>>>(wv, W0 + 5242880, 1048576);
  rmsnorm_k<<<4096, 256, 0, stream>>>(x, ln1, HBF);
  gemm_bt<0><<<768, 256, 0, stream>>>(HBF, W0, nullptr, QKV, nullptr, nullptr, 4096, 3072, 2048);
  qknorm_rope_k<<<4096, 256, 0, stream>>>(QKV, qnw, knw, COS, SIN, QRO, KRO);
  vtrans_k<<<256, 256, 0, stream>>>(QKV, VT);
  cvt_k<<<4096, 256, 0, stream>>>(wo, W0, 4194304);     // overwrites wqkv (dead)
  attn_kernel<<<dim3(32, 16, 2), 256, 0, stream>>>(QRO, KRO, VT, ATT);
  gemm_bt<1><<<512, 256, 0, stream>>>(ATT, W0, nullptr, nullptr, out, x, 4096, 2048, 2048);
  rmsnorm_k<<<4096, 256, 0, stream>>>(out, ln2, HBF);
  cvt2_k<<<16384, 256, 0, stream>>>(w1, W13I, 0);       // region A dead now
  cvt2_k<<<16384, 256, 0, stream>>>(w3, W13I, 1);
  gemm_sw<<<1024, 512, 0, stream>>>(HBF, W13I, ACT);
  cvt_k<<<16384, 256, 0, stream>>>(w2, W2B, 16777216);
  gemm_bt<1><<<512, 256, 0, stream>>>(ACT, W2B, nullptr, nullptr, out, out, 4096, 2048, 8192);
}

// Round 13
// 619.136 us; speedup vs baseline: 1.0700x; 1.0700x over previous
//
#include <hip/hip_runtime.h>
#include <hip/hip_bf16.h>
#include <cstdint>

// Problem constants
#define BB 2
#define SS 2048
#define HID 2048
#define NH 16
#define NKV 4
#define HD 128
#define SCALE_ 0.08838834764831845f   // 128^-0.5
#define EPS_ 1e-6f

typedef __bf16 bf16;
typedef __attribute__((ext_vector_type(8))) __bf16 bf16x8;
typedef __attribute__((ext_vector_type(4))) __bf16 bf16x4;
typedef __attribute__((ext_vector_type(4))) float f32x4;

__device__ __forceinline__ void g2l16(const bf16* src, void* dst) {
  __builtin_amdgcn_global_load_lds(
      (const __attribute__((address_space(1))) void*)src,
      (__attribute__((address_space(3))) void*)dst, 16, 0, 0);
}

// ---------------- fused f32 -> bf16 convert: wq|wk|wv -> W0 ----------------
// 6291456 elems total: [0,4194304) wq, [4194304,5242880) wk, [5242880,6291456) wv.
// Boundaries are multiples of 1024 threads -> branches are block-uniform.
__global__ __launch_bounds__(256) void cvt_qkv_k(const float* __restrict__ wq, const float* __restrict__ wk,
                                                 const float* __restrict__ wv, bf16* __restrict__ dst) {
  int i = (blockIdx.x * 256 + threadIdx.x) * 4;
  const float* s;
  if (i < 4194304) s = wq + i;
  else if (i < 5242880) s = wk + (i - 4194304);
  else s = wv + (i - 5242880);
  f32x4 v = *(const f32x4*)s;
  bf16x4 o;
  o[0] = (bf16)v[0]; o[1] = (bf16)v[1]; o[2] = (bf16)v[2]; o[3] = (bf16)v[3];
  *(bf16x4*)(dst + i) = o;
}

// ---------------- fused f32 -> bf16 convert: w1|w3 -> W13 ----------------
// 33554432 elems: first half w1, second half w3 (concatenated, R11 layout).
__global__ __launch_bounds__(256) void cvt13_k(const float* __restrict__ w1, const float* __restrict__ w3,
                                               bf16* __restrict__ dst) {
  int i = (blockIdx.x * 256 + threadIdx.x) * 4;
  const float* s = (i < 16777216) ? (w1 + i) : (w3 + (i - 16777216));
  f32x4 v = *(const f32x4*)s;
  bf16x4 o;
  o[0] = (bf16)v[0]; o[1] = (bf16)v[1]; o[2] = (bf16)v[2]; o[3] = (bf16)v[3];
  *(bf16x4*)(dst + i) = o;
}

// ---------------- f32 -> bf16 convert ----------------
__global__ __launch_bounds__(256) void cvt_k(const float* __restrict__ src, bf16* __restrict__ dst, int n) {
  int i = (blockIdx.x * 256 + threadIdx.x) * 4;
  if (i >= n) return;
  f32x4 v = *(const f32x4*)(src + i);
  bf16x4 o;
  o[0] = (bf16)v[0]; o[1] = (bf16)v[1]; o[2] = (bf16)v[2]; o[3] = (bf16)v[3];
  *(bf16x4*)(dst + i) = o;
}

// ---------------- RMSNorm: f32 row[2048] -> bf16 ----------------
__global__ __launch_bounds__(256) void rmsnorm_k(const float* __restrict__ X, const float* __restrict__ W,
                                                 bf16* __restrict__ Out) {
  const int row = blockIdx.x;
  const float* xr = X + (size_t)row * 2048;
  const int t = threadIdx.x;
  f32x4 a = *(const f32x4*)(xr + t * 8);
  f32x4 b = *(const f32x4*)(xr + t * 8 + 4);
  float ss = a[0]*a[0] + a[1]*a[1] + a[2]*a[2] + a[3]*a[3]
           + b[0]*b[0] + b[1]*b[1] + b[2]*b[2] + b[3]*b[3];
  #pragma unroll
  for (int m = 1; m <= 32; m <<= 1) ss += __shfl_xor(ss, m);
  __shared__ float red[4];
  if ((t & 63) == 0) red[t >> 6] = ss;
  __syncthreads();
  ss = red[0] + red[1] + red[2] + red[3];
  float sc = rsqrtf(ss * (1.f / 2048.f) + EPS_);
  const float* wp = W + t * 8;
  float v[8] = {a[0], a[1], a[2], a[3], b[0], b[1], b[2], b[3]};
  bf16x8 o;
  #pragma unroll
  for (int j = 0; j < 8; j++) o[j] = (bf16)(v[j] * sc * wp[j]);
  *(bf16x8*)(Out + (size_t)row * 2048 + t * 8) = o;
}

// ---------------- QK-RMSNorm + RoPE (cos/sin computed in-block, R13) ----------------
// QKV row: [q 2048 | k 512 | v 512]. Norm q over 2048, k over 512, rope first 64 dims/head.
__global__ __launch_bounds__(256) void qknorm_rope_k(const bf16* __restrict__ QKV,
                                                     const float* __restrict__ QW, const float* __restrict__ KW,
                                                     bf16* __restrict__ Qo, bf16* __restrict__ Ko) {
  const int row = blockIdx.x;          // b*S+s
  const int s = row & (SS - 1);
  const bf16* qr = QKV + (size_t)row * 3072;
  const int t = threadIdx.x;

  __shared__ float cb_s[32], sb_s[32];
  if (t < 32) {
    float inv = powf(10000.f, -(float)t / 32.f);
    float f = (float)s * inv;
    cb_s[t] = cosf(f);
    sb_s[t] = sinf(f);
  }

  bf16x8 qv = *(const bf16x8*)(qr + t * 8);
  float qvf[8];
  float ssq = 0.f, ssk = 0.f;
  #pragma unroll
  for (int j = 0; j < 8; j++) { qvf[j] = (float)qv[j]; ssq += qvf[j] * qvf[j]; }
  float kvf[8];
  if (t < 64) {
    bf16x8 kv = *(const bf16x8*)(qr + 2048 + t * 8);
    #pragma unroll
    for (int j = 0; j < 8; j++) { kvf[j] = (float)kv[j]; ssk += kvf[j] * kvf[j]; }
  }
  #pragma unroll
  for (int m = 1; m <= 32; m <<= 1) { ssq += __shfl_xor(ssq, m); ssk += __shfl_xor(ssk, m); }
  __shared__ float redq[4], redk[4];
  if ((t & 63) == 0) { redq[t >> 6] = ssq; redk[t >> 6] = ssk; }
  __syncthreads();
  ssq = redq[0] + redq[1] + redq[2] + redq[3];
  ssk = redk[0] + redk[1] + redk[2] + redk[3];
  const float scq = rsqrtf(ssq * (1.f / 2048.f) + EPS_);
  const float sck = rsqrtf(ssk * (1.f / 512.f) + EPS_);

  // q: elems e..e+7
  {
    int e = t * 8, dh = e & 127;
    float nv[8];
    #pragma unroll
    for (int j = 0; j < 8; j++) nv[j] = qvf[j] * scq * QW[e + j];
    if (dh < 64) {
      int pe = (dh < 32) ? e + 32 : e - 32;
      bf16x8 pv = *(const bf16x8*)(qr + pe);
      #pragma unroll
      for (int j = 0; j < 8; j++) {
        float pf = (float)pv[j] * scq * QW[pe + j];
        float c = cb_s[(dh + j) & 31], sn = sb_s[(dh + j) & 31];
        nv[j] = (dh < 32) ? (nv[j] * c - pf * sn) : (nv[j] * c + pf * sn);
      }
    }
    bf16x8 o;
    #pragma unroll
    for (int j = 0; j < 8; j++) o[j] = (bf16)nv[j];
    *(bf16x8*)(Qo + (size_t)row * 2048 + e) = o;
  }
  // k: threads 0..63
  if (t < 64) {
    int e = t * 8, dh = e & 127;
    float nv[8];
    #pragma unroll
    for (int j = 0; j < 8; j++) nv[j] = kvf[j] * sck * KW[e + j];
    if (dh < 64) {
      int pe = (dh < 32) ? e + 32 : e - 32;
      bf16x8 pv = *(const bf16x8*)(qr + 2048 + pe);
      #pragma unroll
      for (int j = 0; j < 8; j++) {
        float pf = (float)pv[j] * sck * KW[pe + j];
        float c = cb_s[(dh + j) & 31], sn = sb_s[(dh + j) & 31];
        nv[j] = (dh < 32) ? (nv[j] * c - pf * sn) : (nv[j] * c + pf * sn);
      }
    }
    bf16x8 o;
    #pragma unroll
    for (int j = 0; j < 8; j++) o[j] = (bf16)nv[j];
    *(bf16x8*)(Ko + (size_t)row * 512 + e) = o;
  }
}

// ---------------- V transpose: qkv v-part -> Vt[B,HK,D,S] ----------------
__global__ __launch_bounds__(256) void vtrans_k(const bf16* __restrict__ QKV, bf16* __restrict__ Vt) {
  const int blk = blockIdx.x;              // B*HK*(S/64) = 256
  const int st = blk & 31, kh = (blk >> 5) & 3, b = blk >> 7;
  const int s0 = st << 6;
  __shared__ __align__(16) bf16 tile[64][136];
  const int t = threadIdx.x;
  {
    const int s = t >> 2, c = (t & 3) * 32;
    const bf16* src = QKV + (size_t)(b * SS + s0 + s) * 3072 + 2560 + kh * 128 + c;
    #pragma unroll
    for (int j = 0; j < 4; j++)
      *(bf16x8*)(&tile[s][c + j * 8]) = *(const bf16x8*)(src + j * 8);
  }
  __syncthreads();
  {
    const int d = t >> 1, sh = (t & 1) * 32;
    bf16* dst = Vt + ((size_t)(b * NKV + kh) * HD + d) * SS + s0 + sh;
    #pragma unroll
    for (int j4 = 0; j4 < 4; j4++) {
      bf16x8 o;
      #pragma unroll
      for (int jj = 0; jj < 8; jj++) o[jj] = tile[sh + j4 * 8 + jj][d];
      *(bf16x8*)(dst + j4 * 8) = o;
    }
  }
}

// ---------------- GEMM: C[M,N] = A[M,K] @ W[N,K]^T (128x128, BK=64) ----------------
// Supertile column-groups-of-8 + XCD swizzle (R9: 5.4x fetch cut); 16x16 MFMA;
// chunk^=(row&7) swizzle; global_load_lds w16.
//  - non-dual (EPI 0/1): double-buffered issue-early/wait-late (64KB LDS, 2 blocks/CU) [R10 win]
//  - dual (EPI 2): single-buffer 2-barrier (48KB LDS, 3 blocks/CU, 3 waves/SIMD) [R9: 241us/1141TF;
//    every deeper pipeline tried (R3/5/6/10/12) lost to this via the occupancy cliff]
// EPI 0: store bf16.  EPI 1: Cf = resid + acc.  EPI 2: dual-B, Cb = silu(accW0)*accW1.
template <int EPI>
__global__ __launch_bounds__(256, 2) void gemm_bt(const bf16* __restrict__ A, const bf16* __restrict__ W0,
                                                  const bf16* __restrict__ W1, bf16* __restrict__ Cb,
                                                  float* __restrict__ Cf, const float* __restrict__ resid,
                                                  int M, int N, int K) {
  constexpr bool DUAL = (EPI == 2);
  constexpr bool DBUF = !DUAL;
  constexpr int TB = DUAL ? 49152 : 32768;
  __shared__ __align__(16) char smem[DBUF ? 2 * TB : TB];

  const int nbm = M >> 7;
  const int nwg = gridDim.x;
  const int per = nwg >> 3;
  const int bid = blockIdx.x;
  const int swz = (bid & 7) * per + (bid >> 3);
  const int gsz = nbm << 3;
  const int g = swz / gsz;
  const int rr = swz - g * gsz;
  const int by = rr >> 3;
  const int bx = (g << 3) + (rr & 7);
  const int m0 = by << 7, n0 = bx << 7;

  const int t = threadIdx.x;
  const int lane = t & 63, wid = t >> 6;
  const int wr = (wid >> 1) * 64, wc = (wid & 1) * 64;
  const int lr = lane & 15, lg = lane >> 4;

  f32x4 acc[4][4], acc3[4][4];
  #pragma unroll
  for (int i = 0; i < 4; i++)
    #pragma unroll
    for (int j = 0; j < 4; j++) {
      acc[i][j] = (f32x4)0.f;
      if constexpr (DUAL) acc3[i][j] = (f32x4)0.f;
    }

  const int srow = t >> 3;
  const int sc8 = t & 7;

  auto stage = [&](int k0, char* base) {
    #pragma unroll
    for (int i = 0; i < 4; i++) {
      int row = i * 32 + srow;
      int csw = sc8 ^ (row & 7);
      g2l16(A + (size_t)(m0 + row) * K + k0 + csw * 8, base + i * 4096 + t * 16);
    }
    #pragma unroll
    for (int i = 0; i < 4; i++) {
      int row = i * 32 + srow;
      int csw = sc8 ^ (row & 7);
      g2l16(W0 + (size_t)(n0 + row) * K + k0 + csw * 8, base + 16384 + i * 4096 + t * 16);
    }
    if constexpr (DUAL) {
      #pragma unroll
      for (int i = 0; i < 4; i++) {
        int row = i * 32 + srow;
        int csw = sc8 ^ (row & 7);
        g2l16(W1 + (size_t)(n0 + row) * K + k0 + csw * 8, base + 32768 + i * 4096 + t * 16);
      }
    }
  };

  auto compute = [&](const char* cur) {
    #pragma unroll
    for (int kk = 0; kk < 2; kk++) {
      bf16x8 af[4];
      #pragma unroll
      for (int mi = 0; mi < 4; mi++) {
        int row = wr + mi * 16 + lr;
        int ch = (kk * 4 + lg) ^ (row & 7);
        af[mi] = *(const bf16x8*)(cur + row * 128 + ch * 16);
      }
      #pragma unroll
      for (int ni = 0; ni < 4; ni++) {
        int rowb = wc + ni * 16 + lr;
        int chb = (kk * 4 + lg) ^ (rowb & 7);
        bf16x8 bb = *(const bf16x8*)(cur + 16384 + rowb * 128 + chb * 16);
        #pragma unroll
        for (int mi = 0; mi < 4; mi++)
          acc[mi][ni] = __builtin_amdgcn_mfma_f32_16x16x32_bf16(af[mi], bb, acc[mi][ni], 0, 0, 0);
        if constexpr (DUAL) {
          bf16x8 b3 = *(const bf16x8*)(cur + 32768 + rowb * 128 + chb * 16);
          #pragma unroll
          for (int mi = 0; mi < 4; mi++)
            acc3[mi][ni] = __builtin_amdgcn_mfma_f32_16x16x32_bf16(af[mi], b3, acc3[mi][ni], 0, 0, 0);
        }
      }
    }
  };

  if constexpr (DBUF) {
    stage(0, smem);
    asm volatile("s_waitcnt vmcnt(0)" ::: "memory");
    __builtin_amdgcn_s_barrier();
    for (int k0 = 0; k0 < K; k0 += 64) {
      char* cur = smem + (((k0 >> 6) & 1) ? TB : 0);
      char* nxt = smem + (((k0 >> 6) & 1) ? 0 : TB);
      if (k0 + 64 < K) stage(k0 + 64, nxt);
      compute(cur);
      asm volatile("s_waitcnt vmcnt(0)" ::: "memory");
      __builtin_amdgcn_s_barrier();
    }
  } else {
    for (int k0 = 0; k0 < K; k0 += 64) {
      __syncthreads();
      stage(k0, smem);
      __syncthreads();
      compute(smem);
    }
  }

  // epilogue: C row = (lane>>4)*4 + r, col = lane&15  [verified m89 layout]
  #pragma unroll
  for (int mi = 0; mi < 4; mi++)
    #pragma unroll
    for (int ni = 0; ni < 4; ni++)
      #pragma unroll
      for (int r = 0; r < 4; r++) {
        int m = m0 + wr + mi * 16 + lg * 4 + r;
        int n = n0 + wc + ni * 16 + lr;
        size_t idx = (size_t)m * N + n;
        if constexpr (EPI == 0) {
          Cb[idx] = (bf16)acc[mi][ni][r];
        } else if constexpr (EPI == 1) {
          Cf[idx] = resid[idx] + acc[mi][ni][r];
        } else {
          float g_ = acc[mi][ni][r], u = acc3[mi][ni][r];
          Cb[idx] = (bf16)(g_ * u / (1.f + __expf(-g_)));
        }
      }
}

// ---------------- Sliding-window GQA flash attention ----------------
// grid (S/64, H, B); 4 waves, each owns 16 q rows. K LDS [64][128] swz, Vt LDS [128][64] swz.
__global__ __launch_bounds__(256, 2) void attn_kernel(const bf16* __restrict__ Q, const bf16* __restrict__ Kr,
                                                      const bf16* __restrict__ Vt, bf16* __restrict__ O) {
  __shared__ __align__(16) char smem[41984];   // 16K K + 16K V + 4*2304 P
  const int qt = blockIdx.x, h = blockIdx.y, b = blockIdx.z;
  const int kh = h >> 2;
  const int q0 = qt << 6;
  const int t = threadIdx.x, lane = t & 63, wid = t >> 6;
  const int lr = lane & 15, lg = lane >> 4;

  bf16x8 qf[4];
  {
    const bf16* qb = Q + (((size_t)b * SS + q0 + wid * 16 + lr) * NH + h) * HD;
    #pragma unroll
    for (int c = 0; c < 4; c++) qf[c] = *(const bf16x8*)(qb + c * 32 + lg * 8);
  }
  f32x4 of[8];
  #pragma unroll
  for (int i = 0; i < 8; i++) of[i] = (f32x4)0.f;
  float m_[4] = {-1e30f, -1e30f, -1e30f, -1e30f};
  float l_[4] = {0.f, 0.f, 0.f, 0.f};

  const int kt_lo = qt >= 8 ? qt - 8 : 0;
  for (int kt = kt_lo; kt <= qt; kt++) {
    const int k0 = kt << 6;
    __syncthreads();
    {   // stage K tile [64][128], 16 chunks/row, swz ^(row&7)
      int rb = t >> 4, c = t & 15;
      #pragma unroll
      for (int i = 0; i < 4; i++) {
        int r = i * 16 + rb;
        int csw = c ^ (r & 7);
        g2l16(Kr + (((size_t)b * SS + k0 + r) * NKV + kh) * HD + csw * 8, smem + i * 4096 + t * 16);
      }
    }
    {   // stage Vt tile [128][64], 8 chunks/row, swz ^(row&7)
      int rb = t >> 3, c = t & 7;
      #pragma unroll
      for (int i = 0; i < 4; i++) {
        int r = i * 32 + rb;
        int csw = c ^ (r & 7);
        g2l16(Vt + ((size_t)(b * NKV + kh) * HD + r) * SS + k0 + csw * 8, smem + 16384 + i * 4096 + t * 16);
      }
    }
    __syncthreads();

    f32x4 sf[4];
    #pragma unroll
    for (int nt = 0; nt < 4; nt++) {
      sf[nt] = (f32x4)0.f;
      #pragma unroll
      for (int c = 0; c < 4; c++) {
        int row = nt * 16 + lr;
        int ch = (c * 4 + lg) ^ (row & 7);
        bf16x8 kf = *(const bf16x8*)(smem + row * 256 + ch * 16);
        sf[nt] = __builtin_amdgcn_mfma_f32_16x16x32_bf16(qf[c], kf, sf[nt], 0, 0, 0);
      }
    }
    // online softmax (rows = lg*4 + r, cols = k0 + nt*16 + lr)
    #pragma unroll
    for (int r = 0; r < 4; r++) {
      int q = q0 + wid * 16 + lg * 4 + r;
      float mx = -1e30f;
      #pragma unroll
      for (int nt = 0; nt < 4; nt++) {
        int k = k0 + nt * 16 + lr;
        float s = sf[nt][r] * SCALE_;
        s = (k <= q && k + 512 >= q) ? s : -1e30f;
        sf[nt][r] = s;
        mx = fmaxf(mx, s);
      }
      mx = fmaxf(mx, __shfl_xor(mx, 1));
      mx = fmaxf(mx, __shfl_xor(mx, 2));
      mx = fmaxf(mx, __shfl_xor(mx, 4));
      mx = fmaxf(mx, __shfl_xor(mx, 8));
      float mnew = fmaxf(m_[r], mx);
      float corr = __expf(m_[r] - mnew);
      float rs = 0.f;
      #pragma unroll
      for (int nt = 0; nt < 4; nt++) {
        float p = __expf(sf[nt][r] - mnew);
        sf[nt][r] = p;
        rs += p;
      }
      rs += __shfl_xor(rs, 1); rs += __shfl_xor(rs, 2);
      rs += __shfl_xor(rs, 4); rs += __shfl_xor(rs, 8);
      l_[r] = l_[r] * corr + rs;
      m_[r] = mnew;
      #pragma unroll
      for (int dt = 0; dt < 8; dt++) of[dt][r] *= corr;
    }
    // P through LDS (per-wave strip, pad 72) to re-fragment as MFMA A operand
    bf16* Pl = (bf16*)(smem + 32768 + wid * 2304);
    #pragma unroll
    for (int nt = 0; nt < 4; nt++)
      #pragma unroll
      for (int r = 0; r < 4; r++)
        Pl[(lg * 4 + r) * 72 + nt * 16 + lr] = (bf16)sf[nt][r];
    bf16x8 pf[2];
    #pragma unroll
    for (int c = 0; c < 2; c++) pf[c] = *(const bf16x8*)(Pl + lr * 72 + c * 32 + lg * 8);
    #pragma unroll
    for (int dt = 0; dt < 8; dt++) {
      #pragma unroll
      for (int c = 0; c < 2; c++) {
        int row = dt * 16 + lr;
        int ch = (c * 4 + lg) ^ (row & 7);
        bf16x8 vf = *(const bf16x8*)(smem + 16384 + row * 128 + ch * 16);
        of[dt] = __builtin_amdgcn_mfma_f32_16x16x32_bf16(pf[c], vf, of[dt], 0, 0, 0);
      }
    }
  }
  #pragma unroll
  for (int dt = 0; dt < 8; dt++)
    #pragma unroll
    for (int r = 0; r < 4; r++) {
      int q = q0 + wid * 16 + lg * 4 + r;
      O[(((size_t)b * SS + q) * NH + h) * HD + dt * 16 + lr] = (bf16)(of[dt][r] / l_[r]);
    }
}

// ---------------- launch ----------------
extern "C" void kernel_launch(void* const* d_in, const int* in_sizes, int n_in,
                              void* d_out, int out_size, void* d_ws, size_t ws_size,
                              hipStream_t stream) {
  (void)in_sizes; (void)n_in; (void)out_size; (void)ws_size;
  const float* x   = (const float*)d_in[0];
  const float* wq  = (const float*)d_in[1];
  const float* wk  = (const float*)d_in[2];
  const float* wv  = (const float*)d_in[3];
  const float* wo  = (const float*)d_in[4];
  const float* qnw = (const float*)d_in[5];
  const float* knw = (const float*)d_in[6];
  const float* ln1 = (const float*)d_in[7];
  const float* ln2 = (const float*)d_in[8];
  const float* w1  = (const float*)d_in[9];
  const float* w2  = (const float*)d_in[10];
  const float* w3  = (const float*)d_in[11];
  float* out = (float*)d_out;
  char* ws = (char*)d_ws;

  // workspace layout (region A reused across phases; all reads precede overwrites in stream order)
  bf16* W0  = (bf16*)(ws + 0);            // wqkv bf16 [3072,2048] -> wo -> w1|w3 -> w2
  bf16* QKV = (bf16*)(ws + 12582912);     // [4096,3072] bf16
  bf16* QRO = (bf16*)(ws + 37748736);     // [4096,2048] bf16
  bf16* KRO = (bf16*)(ws + 54525952);     // [4096,512] bf16
  bf16* ATT = (bf16*)(ws + 58720256);     // [4096,2048] bf16
  bf16* VT  = (bf16*)(ws + 75497472);     // [B,HK,D,S] bf16
  bf16* HBF = (bf16*)(ws + 79691776);     // [4096,2048] bf16 (ln1 out, later ln2 out)
  bf16* ACT = (bf16*)(ws + 96468992);     // [4096,8192] bf16
  bf16* W13 = (bf16*)ws;                  // w1 then w3, after region A is dead
  bf16* W2B = (bf16*)ws;                  // w2, after dual gemm

  cvt_qkv_k<<<6144, 256, 0, stream>>>(wq, wk, wv, W0);
  rmsnorm_k<<<4096, 256, 0, stream>>>(x, ln1, HBF);
  gemm_bt<0><<<768, 256, 0, stream>>>(HBF, W0, nullptr, QKV, nullptr, nullptr, 4096, 3072, 2048);
  qknorm_rope_k<<<4096, 256, 0, stream>>>(QKV, qnw, knw, QRO, KRO);
  vtrans_k<<<256, 256, 0, stream>>>(QKV, VT);
  cvt_k<<<4096, 256, 0, stream>>>(wo, W0, 4194304);     // overwrites wqkv (dead)
  attn_kernel<<<dim3(32, 16, 2), 256, 0, stream>>>(QRO, KRO, VT, ATT);
  gemm_bt<1><<<512, 256, 0, stream>>>(ATT, W0, nullptr, nullptr, out, x, 4096, 2048, 2048);
  rmsnorm_k<<<4096, 256, 0, stream>>>(out, ln2, HBF);
  cvt13_k<<<32768, 256, 0, stream>>>(w1, w3, W13);      // region A dead now
  gemm_bt<2><<<2048, 256, 0, stream>>>(HBF, W13, W13 + 16777216, ACT, nullptr, nullptr, 4096, 8192, 2048);
  cvt_k<<<16384, 256, 0, stream>>>(w2, W2B, 16777216);
  gemm_bt<1><<<512, 256, 0, stream>>>(ACT, W2B, nullptr, nullptr, out, out, 4096, 2048, 8192);
}